// Round 1
// baseline (341.278 us; speedup 1.0000x reference)
//
#include <hip/hip_runtime.h>

// HashGrid2D: out[i, :] = table[hash(positions[i]), :]
// hash = ((floor(x)*73856093) ^ (floor(y)*19349663)) & (2^19 - 1)
// Low 19 bits of the int64 products == low 19 bits of 32-bit wrapping
// products, and both operands are non-negative, so uint32 math is exact.

#define HASH_MASK ((1u << 19) - 1u)

__global__ __launch_bounds__(256) void HashGrid2D_37383395344981_kernel(
    const float2* __restrict__ pos,
    const float4* __restrict__ table,   // HASH_SIZE x 8 float4 (=32 floats)
    float4* __restrict__ out,           // N x 8 float4
    int n)
{
    int gid = blockIdx.x * blockDim.x + threadIdx.x;
    int r = gid >> 3;          // output row (position index)
    int c = gid & 7;           // which float4 within the 32-float row
    if (r >= n) return;

    float2 p = pos[r];         // 8 lanes share this 8B load (same cache line)
    unsigned ix = (unsigned)(int)floorf(p.x);
    unsigned iy = (unsigned)(int)floorf(p.y);
    unsigned h = ((ix * 73856093u) ^ (iy * 19349663u)) & HASH_MASK;

    out[(size_t)r * 8 + c] = table[(size_t)h * 8 + c];
}

extern "C" void kernel_launch(void* const* d_in, const int* in_sizes, int n_in,
                              void* d_out, int out_size, void* d_ws, size_t ws_size,
                              hipStream_t stream) {
    const float2* pos   = (const float2*)d_in[0];
    const float4* table = (const float4*)d_in[1];
    float4* out = (float4*)d_out;

    int n = in_sizes[0] / 2;           // N positions (each has x,y)
    long long threads = (long long)n * 8;
    int block = 256;
    int grid = (int)((threads + block - 1) / block);

    HashGrid2D_37383395344981_kernel<<<grid, block, 0, stream>>>(pos, table, out, n);
}

// Round 3
// 332.351 us; speedup vs baseline: 1.0269x; 1.0269x over previous
//
#include <hip/hip_runtime.h>

// HashGrid2D: out[i, :] = table[hash(positions[i]), :]
// hash = ((floor(x)*73856093) ^ (floor(y)*19349663)) & (2^19 - 1)
// uint32 wrapping mul is exact for the low 19 bits; operands non-negative.
//
// R1 -> R2: 341us at ~1.5 TB/s effective. Theory: 256MB streaming write +
// 16MB pos read thrash the 256MB L3, evicting the 64MB table, so gathers
// become random HBM reads. Fix: non-temporal store for out, non-temporal
// load for pos, keeping L3 dedicated to the table.
// R2 -> R3: __builtin_nontemporal_* requires native clang vector types,
// not HIP_vector_type — use ext_vector_type floats.

#define HASH_MASK ((1u << 19) - 1u)

typedef float vfloat2 __attribute__((ext_vector_type(2)));
typedef float vfloat4 __attribute__((ext_vector_type(4)));

__global__ __launch_bounds__(256) void HashGrid2D_37383395344981_kernel(
    const vfloat2* __restrict__ pos,
    const vfloat4* __restrict__ table,   // HASH_SIZE x 8 vfloat4 (=32 floats)
    vfloat4* __restrict__ out,           // N x 8 vfloat4
    int n)
{
    int gid = blockIdx.x * blockDim.x + threadIdx.x;
    int r = gid >> 3;          // output row (position index)
    int c = gid & 7;           // which float4 within the 32-float row
    if (r >= n) return;

    // Streaming read: don't let 16MB of positions pollute L2/L3.
    vfloat2 p = __builtin_nontemporal_load(&pos[r]);
    unsigned ix = (unsigned)(int)floorf(p.x);
    unsigned iy = (unsigned)(int)floorf(p.y);
    unsigned h = ((ix * 73856093u) ^ (iy * 19349663u)) & HASH_MASK;

    // Cached gather: the 64MB table should stay resident in L3.
    vfloat4 v = table[(size_t)h * 8 + c];

    // Streaming write: 256MB write-once must not evict the table.
    __builtin_nontemporal_store(v, &out[(size_t)r * 8 + c]);
}

extern "C" void kernel_launch(void* const* d_in, const int* in_sizes, int n_in,
                              void* d_out, int out_size, void* d_ws, size_t ws_size,
                              hipStream_t stream) {
    const vfloat2* pos   = (const vfloat2*)d_in[0];
    const vfloat4* table = (const vfloat4*)d_in[1];
    vfloat4* out = (vfloat4*)d_out;

    int n = in_sizes[0] / 2;           // N positions (each has x,y)
    long long threads = (long long)n * 8;
    int block = 256;
    int grid = (int)((threads + block - 1) / block);

    HashGrid2D_37383395344981_kernel<<<grid, block, 0, stream>>>(pos, table, out, n);
}